// Round 1
// baseline (2302.296 us; speedup 1.0000x reference)
//
#include <hip/hip_runtime.h>

typedef __bf16 bf16x8 __attribute__((ext_vector_type(8)));
typedef float f32x4 __attribute__((ext_vector_type(4)));

#define TSTEPS 7
#define FEAT 60
#define MTILE 64
#define THREADS 256

// ---- preprocessing: transpose + bf16-cast weights into workspace ----
// Ut: [1024][256] bf16, row n = gate-column of U (U is [256][1024] row-major)
__global__ void prep_U_kernel(const float* __restrict__ U, __bf16* __restrict__ Ut) {
    int idx = blockIdx.x * blockDim.x + threadIdx.x;  // 1024*256
    int n = idx >> 8;
    int k = idx & 255;
    Ut[idx] = (__bf16)U[k * 1024 + n];
}

// Wt: [1024][64] bf16, K padded 60->64 with zeros
__global__ void prep_W_kernel(const float* __restrict__ W, __bf16* __restrict__ Wt) {
    int idx = blockIdx.x * blockDim.x + threadIdx.x;  // 1024*64
    int n = idx >> 6;
    int k = idx & 63;
    float v = (k < FEAT) ? W[k * 1024 + n] : 0.0f;
    Wt[idx] = (__bf16)v;
}

__device__ __forceinline__ float sigm(float z) {
    return __builtin_amdgcn_rcpf(1.0f + __expf(-z));
}
// tanh via 1 - 2/(e^{2z}+1): no NaN at |z| large (inf -> 1, 0 -> -1)
__device__ __forceinline__ float tanh_(float z) {
    return 1.0f - 2.0f * __builtin_amdgcn_rcpf(__expf(2.0f * z) + 1.0f);
}

// One WG = 64 batch rows, 4 waves. Wave w owns gate-units u in [64w, 64w+64).
// h (bf16) lives in LDS (A-operand for next step); c lives in registers in
// MFMA C/D layout. U/W fragments stream from global (L2-resident).
__global__ __launch_bounds__(THREADS, 1)
void lstm_kernel(const float* __restrict__ x, const __bf16* __restrict__ Ut,
                 const __bf16* __restrict__ Wt, const float* __restrict__ bias,
                 float* __restrict__ out, int B) {
    // x tile: [t][m][72] bf16 (pad 60->64 zeroed, 72 stride breaks bank aliasing)
    __shared__ __align__(16) __bf16 x_lds[TSTEPS][MTILE][72];
    // h tile: [m][264] bf16 (stride 264 -> 4-bank offset per row)
    __shared__ __align__(16) __bf16 h_lds[MTILE][264];

    const int tid = threadIdx.x;
    const int wave = tid >> 6;
    const int lane = tid & 63;
    const int quad = lane >> 4;
    const int l16 = lane & 15;
    const int r0 = blockIdx.x * MTILE;

    // ---- stage x tile (coalesced global read, bf16 convert) ----
    for (int i = tid; i < MTILE * TSTEPS * FEAT; i += THREADS) {
        int m = i / (TSTEPS * FEAT);
        int rem = i - m * (TSTEPS * FEAT);
        int t = rem / FEAT;
        int f = rem - t * FEAT;
        x_lds[t][m][f] = (__bf16)x[(size_t)(r0 + m) * (TSTEPS * FEAT) + rem];
    }
    // zero the K-pad cols 60..63 (must not be NaN garbage: 0*0 in MFMA)
    for (int i = tid; i < MTILE * TSTEPS * 4; i += THREADS) {
        int m = i / (TSTEPS * 4);
        int rem = i - m * (TSTEPS * 4);
        int t = rem >> 2;
        int f = FEAT + (rem & 3);
        x_lds[t][m][f] = (__bf16)0.0f;
    }

    // c state: [uc][mt][reg] in C/D fragment layout
    float c_reg[4][4][4];
#pragma unroll
    for (int uc = 0; uc < 4; ++uc)
#pragma unroll
        for (int mt = 0; mt < 4; ++mt)
#pragma unroll
            for (int r = 0; r < 4; ++r) c_reg[uc][mt][r] = 0.0f;

    // preload bias for this lane's columns
    float bvals[4][4];
#pragma unroll
    for (int uc = 0; uc < 4; ++uc)
#pragma unroll
        for (int g = 0; g < 4; ++g)
            bvals[uc][g] = bias[g * 256 + wave * 64 + uc * 16 + l16];

    __syncthreads();  // x_lds ready

    const size_t HN = (size_t)B * 256;

    for (int t = 0; t < TSTEPS; ++t) {
        // ---- load all A fragments for this step (h: kf 0..7, x_t: kf 8..9) ----
        bf16x8 a[4][10];
        if (t > 0) {
#pragma unroll
            for (int mt = 0; mt < 4; ++mt)
#pragma unroll
                for (int kf = 0; kf < 8; ++kf)
                    a[mt][kf] = *(const bf16x8*)&h_lds[mt * 16 + l16][kf * 32 + quad * 8];
        }
#pragma unroll
        for (int mt = 0; mt < 4; ++mt) {
            a[mt][8] = *(const bf16x8*)&x_lds[t][mt * 16 + l16][quad * 8];
            a[mt][9] = *(const bf16x8*)&x_lds[t][mt * 16 + l16][32 + quad * 8];
        }
        __syncthreads();  // all h_lds reads done before anyone rewrites h

#pragma unroll
        for (int uc = 0; uc < 4; ++uc) {
            const int ncol = wave * 64 + uc * 16 + l16;
            f32x4 acc[4];

            auto gate_gemm = [&](int g) {
                const __bf16* uRow = Ut + (size_t)(g * 256 + ncol) * 256;
                const __bf16* wRow = Wt + (size_t)(g * 256 + ncol) * 64;
                bf16x8 bfr[10];
                if (t > 0) {
#pragma unroll
                    for (int kf = 0; kf < 8; ++kf)
                        bfr[kf] = *(const bf16x8*)(uRow + kf * 32 + quad * 8);
                }
#pragma unroll
                for (int kf = 0; kf < 2; ++kf)
                    bfr[8 + kf] = *(const bf16x8*)(wRow + kf * 32 + quad * 8);
#pragma unroll
                for (int mt = 0; mt < 4; ++mt) acc[mt] = (f32x4){0.f, 0.f, 0.f, 0.f};
                if (t > 0) {
#pragma unroll
                    for (int kf = 0; kf < 8; ++kf)
#pragma unroll
                        for (int mt = 0; mt < 4; ++mt)
                            acc[mt] = __builtin_amdgcn_mfma_f32_16x16x32_bf16(
                                a[mt][kf], bfr[kf], acc[mt], 0, 0, 0);
                }
#pragma unroll
                for (int kf = 0; kf < 2; ++kf)
#pragma unroll
                    for (int mt = 0; mt < 4; ++mt)
                        acc[mt] = __builtin_amdgcn_mfma_f32_16x16x32_bf16(
                            a[mt][8 + kf], bfr[8 + kf], acc[mt], 0, 0, 0);
            };

            float iv[4][4], pg[4][4];
            // gate order: i, g(c), f, o  -> minimizes live gate values
            gate_gemm(0);
#pragma unroll
            for (int mt = 0; mt < 4; ++mt)
#pragma unroll
                for (int r = 0; r < 4; ++r)
                    iv[mt][r] = sigm(acc[mt][r] + bvals[uc][0]);
            gate_gemm(2);
#pragma unroll
            for (int mt = 0; mt < 4; ++mt)
#pragma unroll
                for (int r = 0; r < 4; ++r)
                    pg[mt][r] = iv[mt][r] * tanh_(acc[mt][r] + bvals[uc][2]);
            gate_gemm(1);
#pragma unroll
            for (int mt = 0; mt < 4; ++mt)
#pragma unroll
                for (int r = 0; r < 4; ++r)
                    c_reg[uc][mt][r] =
                        sigm(acc[mt][r] + bvals[uc][1]) * c_reg[uc][mt][r] + pg[mt][r];
            gate_gemm(3);
#pragma unroll
            for (int mt = 0; mt < 4; ++mt)
#pragma unroll
                for (int r = 0; r < 4; ++r) {
                    float cc = c_reg[uc][mt][r];
                    float hv = sigm(acc[mt][r] + bvals[uc][3]) * tanh_(cc);
                    // h_new -> LDS in A-layout position [m][u]
                    h_lds[mt * 16 + quad * 4 + r][ncol] = (__bf16)hv;
                    if (t == TSTEPS - 1) {
                        size_t mg = (size_t)(r0 + mt * 16 + quad * 4 + r);
                        out[mg * 256 + ncol] = hv;          // last_h
                        out[HN + mg * 256 + ncol] = hv;     // h
                        out[2 * HN + mg * 256 + ncol] = cc; // c
                    }
                }
        }
        __syncthreads();  // h writes visible before next step's A loads
    }
}

extern "C" void kernel_launch(void* const* d_in, const int* in_sizes, int n_in,
                              void* d_out, int out_size, void* d_ws, size_t ws_size,
                              hipStream_t stream) {
    const float* x = (const float*)d_in[0];
    const float* W = (const float*)d_in[1];
    const float* U = (const float*)d_in[2];
    const float* b = (const float*)d_in[3];
    float* out = (float*)d_out;

    const int B = in_sizes[0] / (TSTEPS * FEAT);

    __bf16* Ut = (__bf16*)d_ws;                              // 1024*256*2 = 512KB
    __bf16* Wt = (__bf16*)((char*)d_ws + 1024 * 256 * 2);    // 1024*64*2  = 128KB

    prep_U_kernel<<<1024, 256, 0, stream>>>(U, Ut);
    prep_W_kernel<<<256, 256, 0, stream>>>(W, Wt);
    lstm_kernel<<<B / MTILE, THREADS, 0, stream>>>(x, Ut, Wt, b, out, B);
}